// Round 5
// baseline (392.598 us; speedup 1.0000x reference)
//
#include <hip/hip_runtime.h>
#include <hip/hip_bf16.h>
#include <math.h>

typedef unsigned short u16;
typedef unsigned int u32;
typedef __attribute__((ext_vector_type(8))) short bf16x8;   // 8 bf16 = 4 VGPRs
typedef __attribute__((ext_vector_type(4))) float f32x4;

constexpr int Bc = 2, Sc = 2048, Dc = 2048, Hc = 16, HDc = 128;
constexpr int Mc = Bc * Sc;                     // 4096
constexpr float SCALE = 0.08838834764831845f;   // 1/sqrt(128)

__device__ inline u16 f2bf(float f) {
  __hip_bfloat16 h = __float2bfloat16(f);
  return __builtin_bit_cast(u16, h);
}

typedef const __attribute__((address_space(1))) u32 glb_u32;
typedef __attribute__((address_space(3))) u32 lds_u32;
__device__ inline void gload16(const void* g, void* l) {
  // async global->LDS, 16B/lane; LDS dest is wave-uniform base + lane*16
  __builtin_amdgcn_global_load_lds((glb_u32*)g, (lds_u32*)l, 16, 0, 0);
}

// ---------------- fp32 -> bf16 convert (hidden + 4 weights) ----------------
__global__ __launch_bounds__(256) void cvt5(
    const float* __restrict__ s0, u16* __restrict__ d0, int n0,
    const float* __restrict__ s1, u16* __restrict__ d1, int n1,
    const float* __restrict__ s2, u16* __restrict__ d2, int n2,
    const float* __restrict__ s3, u16* __restrict__ d3, int n3,
    const float* __restrict__ s4, u16* __restrict__ d4, int n4) {
  int i = blockIdx.x * 256 + threadIdx.x;   // float4 index
  const float* s; u16* d;
  if (i < n0) { s = s0; d = d0; }
  else { i -= n0;
    if (i < n1) { s = s1; d = d1; }
    else { i -= n1;
      if (i < n2) { s = s2; d = d2; }
      else { i -= n2;
        if (i < n3) { s = s3; d = d3; }
        else { i -= n3;
          if (i >= n4) return;
          s = s4; d = d4; } } } }
  float4 v = reinterpret_cast<const float4*>(s)[i];
  ushort4 o;
  o.x = f2bf(v.x); o.y = f2bf(v.y); o.z = f2bf(v.z); o.w = f2bf(v.w);
  reinterpret_cast<ushort4*>(d)[i] = o;
}

// ---------------- bf16 MFMA GEMM: C[M,N] = A[M,K] * W[N,K]^T + bias --------
// MODE 0: bf16 scatter to [B,H,S,HD], scaled; MODE 1: fp32 [M,N] to d_out;
// MODE 2: bf16 transposed scatter to [B,H,HD,S] (V^T).
constexpr int GBM = 128, GBN = 128, GBK = 64;

template <int MODE>
__global__ __launch_bounds__(256) void gemm_bf16(
    const u16* __restrict__ A, const u16* __restrict__ W,
    const float* __restrict__ bias, void* __restrict__ outp, float scale) {
  __shared__ u16 smem[17408];     // As[8192] | Bs[8192]; epilogue CT[128*136]
  u16* As = smem;
  u16* Bs = smem + 8192;
  char* Asb = (char*)As;
  char* Bsb = (char*)Bs;
  const int t = threadIdx.x;
  const int w = t >> 6, lane = t & 63, g = lane >> 4, c = lane & 15;
  const int wm = w >> 1, wn = w & 1;
  const int m0 = blockIdx.y * GBM, n0 = blockIdx.x * GBN;

  f32x4 acc[4][4];
#pragma unroll
  for (int m = 0; m < 4; ++m)
#pragma unroll
    for (int n = 0; n < 4; ++n) acc[m][n] = 0.f;

  for (int k0 = 0; k0 < Dc; k0 += GBK) {
#pragma unroll
    for (int i = 0; i < 4; ++i) {
      int u = i * 256 + t;
      int row = u >> 3, cu = u & 7;
      int ub = i * 256 + (t & 192);           // wave-uniform unit base
      gload16(A + (size_t)(m0 + row) * Dc + k0 + cu * 8, Asb + ub * 16);
      gload16(W + (size_t)(n0 + row) * Dc + k0 + cu * 8, Bsb + ub * 16);
    }
    __syncthreads();
#pragma unroll
    for (int s = 0; s < 2; ++s) {
      bf16x8 af[4], bfv[4];
#pragma unroll
      for (int m = 0; m < 4; ++m)
        af[m] = *(const bf16x8*)(Asb + (wm * 64 + m * 16 + c) * 128 + s * 64 + g * 16);
#pragma unroll
      for (int n = 0; n < 4; ++n)
        bfv[n] = *(const bf16x8*)(Bsb + (wn * 64 + n * 16 + c) * 128 + s * 64 + g * 16);
#pragma unroll
      for (int m = 0; m < 4; ++m)
#pragma unroll
        for (int n = 0; n < 4; ++n)
          acc[m][n] = __builtin_amdgcn_mfma_f32_16x16x32_bf16(af[m], bfv[n], acc[m][n], 0, 0, 0);
    }
    __syncthreads();
  }

  if (MODE == 2) {
    // transpose through LDS, then coalesced bf16 writes to [B,H,HD,S]
    u16* CT = smem;                           // [128 d][136 pitch] u16
    __syncthreads();
#pragma unroll
    for (int m = 0; m < 4; ++m)
#pragma unroll
      for (int n = 0; n < 4; ++n) {
        int lcol = wn * 64 + n * 16 + c;      // d (local)
        float bv = bias[n0 + lcol];
#pragma unroll
        for (int r = 0; r < 4; ++r) {
          int lrow = wm * 64 + m * 16 + g * 4 + r;   // s (local)
          CT[lcol * 136 + lrow] = f2bf(acc[m][n][r] + bv);
        }
      }
    __syncthreads();
    const int b = m0 >> 11, h = n0 >> 7, s0 = m0 & (Sc - 1);
    u16* op = (u16*)outp;
#pragma unroll
    for (int i = 0; i < 8; ++i) {
      int u = i * 256 + t;
      int d = u >> 4, su = u & 15;
      float4 v4 = *(const float4*)(&CT[d * 136 + su * 8]);
      *(float4*)(&op[((size_t)((b * Hc + h) * HDc) + d) * Sc + s0 + su * 8]) = v4;
    }
    return;
  }

#pragma unroll
  for (int m = 0; m < 4; ++m)
#pragma unroll
    for (int n = 0; n < 4; ++n) {
      int col = n0 + wn * 64 + n * 16 + c;
      float bv = bias[col];
#pragma unroll
      for (int r = 0; r < 4; ++r) {
        int row = m0 + wm * 64 + m * 16 + g * 4 + r;
        float v = (acc[m][n][r] + bv) * scale;
        if (MODE == 0) {
          int b = row >> 11, si = row & (Sc - 1);
          int h = col >> 7, d = col & (HDc - 1);
          ((u16*)outp)[((size_t)((b * Hc + h) * Sc + si)) * HDc + d] = f2bf(v);
        } else {
          ((float*)outp)[(size_t)row * Dc + col] = v;
        }
      }
    }
}

// ---------------- bf16 MFMA flash attention (v4) ----------------
// 512 blocks (XCD-swz, 4 heads/XCD), 256 thr = 4 waves, 32 q-rows/wave
// (two 16-q sets sharing every K/V fragment read -> LDS bytes/MFMA halved).
// K double-buffered, V single-buffered (48KB -> 3 blocks/CU). Swapped QK^T,
// in-register P, shfl redistribution.
__global__ __launch_bounds__(256, 3) void attn_mfma(
    const u16* __restrict__ Q, const u16* __restrict__ K,
    const u16* __restrict__ VT, const float* __restrict__ mask,
    u16* __restrict__ outb) {
  __shared__ u16 Ks[2][64 * 128];   // 16KB each
  __shared__ u16 Vt[64 * 128];      // [d=128][k=64], 16KB
  const int t = threadIdx.x, w = t >> 6, lane = t & 63, g = lane >> 4, c = lane & 15;
  const int bid = blockIdx.x;
  const int nid = (bid & 7) * 64 + (bid >> 3);   // 512%8==0 bijective
  const int bh = nid >> 4;                        // head 0..31 (4 heads/XCD)
  const int q0 = (nid & 15) * 128;                // 128 q-rows per block
  const int bq = bh >> 4, h = bh & 15;
  const u16* Qp = Q + ((size_t)bh << 18);
  const u16* Kp = K + ((size_t)bh << 18);
  const u16* VTp = VT + ((size_t)bh << 18);

  // Q fragments for both q-sets (pre-scaled); B-operand of swapped QK^T
  bf16x8 qf[2][4];
#pragma unroll
  for (int u = 0; u < 2; ++u) {
    int qr = q0 + w * 32 + u * 16 + c;
#pragma unroll
    for (int d0 = 0; d0 < 4; ++d0)
      qf[u][d0] = *(const bf16x8*)(Qp + (size_t)qr * HDc + d0 * 32 + g * 8);
  }

  f32x4 po[2][8];                  // O^T acc: d = m*16+g*4+r, q = set u, col c
#pragma unroll
  for (int u = 0; u < 2; ++u)
#pragma unroll
    for (int m = 0; m < 8; ++m) po[u][m] = 0.f;
  float lsum[2] = {0.f, 0.f};

  auto STAGE_K = [&](int buf, int kt2) {
    const int k0 = kt2 * 64;
#pragma unroll
    for (int i = 0; i < 4; ++i) {
      int u = i * 256 + t, row = u >> 4, p = u & 15;
      int cu = (p & 8) | ((p ^ row) & 7);
      gload16(Kp + (size_t)(k0 + row) * HDc + cu * 8,
              (char*)Ks[buf] + (i * 256 + (t & 192)) * 16);
    }
  };
  auto STAGE_V = [&](int kt2) {
    const int k0 = kt2 * 64;
#pragma unroll
    for (int i = 0; i < 4; ++i) {
      int u = i * 256 + t, d = u >> 3, p = u & 7;
      int cu = (p ^ d) & 7;
      gload16(VTp + (size_t)d * Sc + k0 + cu * 8,
              (char*)Vt + (i * 256 + (t & 192)) * 16);
    }
  };

  const int srcA = ((lane & 16) << 1) | c;       // (g&1)*32 + c
  const int srcB = srcA + 16;
  const bool hiN = lane >= 32;                   // g>>1

  STAGE_K(0, 0);
  __syncthreads();                 // drains prologue K stage

#pragma unroll 1
  for (int kt = 0; kt < 32; ++kt) {
    STAGE_V(kt);                   // safe: all waves passed end-of-tile barrier
    if (kt + 1 < 32) STAGE_K((kt + 1) & 1, kt + 1);

    // QK^T for both q-sets, sharing each K fragment read
    const char* Ksb = (const char*)Ks[kt & 1];
    f32x4 sfr[2][4];
#pragma unroll
    for (int u = 0; u < 2; ++u)
#pragma unroll
      for (int n = 0; n < 4; ++n) sfr[u][n] = 0.f;
    __builtin_amdgcn_s_setprio(1);
#pragma unroll
    for (int ds = 0; ds < 4; ++ds)
#pragma unroll
      for (int n = 0; n < 4; ++n) {
        int row = n * 16 + c;
        int cu = ds * 4 + g;
        int scu = (cu & 8) | ((cu ^ row) & 7);
        bf16x8 kf = *(const bf16x8*)(Ksb + row * 256 + scu * 16);
        sfr[0][n] = __builtin_amdgcn_mfma_f32_16x16x32_bf16(kf, qf[0][ds], sfr[0][n], 0, 0, 0);
        sfr[1][n] = __builtin_amdgcn_mfma_f32_16x16x32_bf16(kf, qf[1][ds], sfr[1][n], 0, 0, 0);
      }
    __builtin_amdgcn_s_setprio(0);

    // no-max softmax + in-register P + shfl redistribution, per q-set
    bf16x8 pf[2][2];
#pragma unroll
    for (int u = 0; u < 2; ++u) {
      const float* mrp = mask + ((size_t)bq * Sc + q0 + w * 32 + u * 16 + c) * Sc + kt * 64;
      float4 mk[4];
#pragma unroll
      for (int n = 0; n < 4; ++n)
        mk[n] = *(const float4*)(mrp + n * 16 + g * 4);
      u32 w01[4], w23[4];
      float lp = 0.f;
#pragma unroll
      for (int n = 0; n < 4; ++n) {
        float p0 = __expf(sfr[u][n][0] + mk[n].x);
        float p1 = __expf(sfr[u][n][1] + mk[n].y);
        float p2 = __expf(sfr[u][n][2] + mk[n].z);
        float p3 = __expf(sfr[u][n][3] + mk[n].w);
        lp += (p0 + p1) + (p2 + p3);
        w01[n] = (u32)f2bf(p0) | ((u32)f2bf(p1) << 16);
        w23[n] = (u32)f2bf(p2) | ((u32)f2bf(p3) << 16);
      }
      lsum[u] += lp;
#pragma unroll
      for (int s2 = 0; s2 < 2; ++s2) {
        u32 a0 = __shfl(w01[s2 * 2], srcA, 64), a0b = __shfl(w01[s2 * 2 + 1], srcA, 64);
        u32 a1 = __shfl(w23[s2 * 2], srcA, 64), a1b = __shfl(w23[s2 * 2 + 1], srcA, 64);
        u32 b0 = __shfl(w01[s2 * 2], srcB, 64), b0b = __shfl(w01[s2 * 2 + 1], srcB, 64);
        u32 b1 = __shfl(w23[s2 * 2], srcB, 64), b1b = __shfl(w23[s2 * 2 + 1], srcB, 64);
        uint4 pw;
        pw.x = hiN ? a0b : a0;
        pw.y = hiN ? a1b : a1;
        pw.z = hiN ? b0b : b0;
        pw.w = hiN ? b1b : b1;
        pf[u][s2] = __builtin_bit_cast(bf16x8, pw);
      }
    }
    __syncthreads();               // drains V(kt) + K(kt+1) stages

    // PV: O^T += V^T * P^T, sharing each V fragment read across q-sets
    __builtin_amdgcn_s_setprio(1);
#pragma unroll
    for (int s2 = 0; s2 < 2; ++s2)
#pragma unroll
      for (int m = 0; m < 8; ++m) {
        int d = m * 16 + c;
        int scuv = ((s2 * 4 + g) ^ (d & 7)) & 7;
        bf16x8 vf = *(const bf16x8*)((const char*)Vt + d * 128 + scuv * 16);
        po[0][m] = __builtin_amdgcn_mfma_f32_16x16x32_bf16(vf, pf[0][s2], po[0][m], 0, 0, 0);
        po[1][m] = __builtin_amdgcn_mfma_f32_16x16x32_bf16(vf, pf[1][s2], po[1][m], 0, 0, 0);
      }
    __builtin_amdgcn_s_setprio(0);
    __syncthreads();               // PV done before next V overwrite
  }

  // final l reduction (lanes c, c+16, c+32, c+48 hold partials of same q)
#pragma unroll
  for (int u = 0; u < 2; ++u) {
    lsum[u] += __shfl_xor(lsum[u], 16, 64);
    lsum[u] += __shfl_xor(lsum[u], 32, 64);
    const float rlq = 1.0f / lsum[u];
    const int qg = q0 + w * 32 + u * 16 + c;
    u16* obase = outb + ((size_t)(bq * Sc + qg)) * Dc + h * HDc;
#pragma unroll
    for (int m = 0; m < 8; ++m) {
      ushort4 o4;
      o4.x = f2bf(po[u][m][0] * rlq);
      o4.y = f2bf(po[u][m][1] * rlq);
      o4.z = f2bf(po[u][m][2] * rlq);
      o4.w = f2bf(po[u][m][3] * rlq);
      *(ushort4*)(obase + m * 16 + g * 4) = o4;
    }
  }
}

// ---------------- launch ----------------
extern "C" void kernel_launch(void* const* d_in, const int* in_sizes, int n_in,
                              void* d_out, int out_size, void* d_ws,
                              size_t ws_size, hipStream_t stream) {
  const float* hs   = (const float*)d_in[0];
  const float* mask = (const float*)d_in[1];
  const float* Wq   = (const float*)d_in[2];
  const float* bqp  = (const float*)d_in[3];
  const float* Wk   = (const float*)d_in[4];
  const float* bkp  = (const float*)d_in[5];
  const float* Wv   = (const float*)d_in[6];
  const float* bvp  = (const float*)d_in[7];
  const float* Wo   = (const float*)d_in[8];
  const float* bop  = (const float*)d_in[9];

  u16* Xb  = (u16*)d_ws;                 // [4096][2048] bf16
  u16* Wqb = Xb + (size_t)Mc * Dc;
  u16* Wkb = Wqb + (size_t)Dc * Dc;
  u16* Wvb = Wkb + (size_t)Dc * Dc;
  u16* Wob = Wvb + (size_t)Dc * Dc;
  u16* qb  = Wob + (size_t)Dc * Dc;      // [B,H,S,HD] bf16 (pre-scaled)
  u16* kb  = qb + (size_t)Mc * Dc;       // [B,H,S,HD] bf16
  u16* vtb = kb + (size_t)Mc * Dc;       // [B,H,HD,S] bf16
  u16* ab  = vtb + (size_t)Mc * Dc;      // [B,S,D] bf16

  const int nh4 = Mc * Dc / 4;
  const int nw4 = Dc * Dc / 4;
  cvt5<<<dim3((nh4 + 4 * nw4) / 256), dim3(256), 0, stream>>>(
      hs, Xb, nh4, Wq, Wqb, nw4, Wk, Wkb, nw4, Wv, Wvb, nw4, Wo, Wob, nw4);

  dim3 blk(256);
  dim3 gg(Dc / GBN, Mc / GBM);           // (16, 32)
  gemm_bf16<0><<<gg, blk, 0, stream>>>(Xb, Wqb, bqp, qb, SCALE);
  gemm_bf16<0><<<gg, blk, 0, stream>>>(Xb, Wkb, bkp, kb, 1.0f);
  gemm_bf16<2><<<gg, blk, 0, stream>>>(Xb, Wvb, bvp, vtb, 1.0f);
  attn_mfma<<<dim3(512), blk, 0, stream>>>(qb, kb, vtb, mask, ab);
  gemm_bf16<1><<<gg, blk, 0, stream>>>(ab, Wob, bop, d_out, 1.0f);
}

// Round 6
// 344.862 us; speedup vs baseline: 1.1384x; 1.1384x over previous
//
#include <hip/hip_runtime.h>
#include <hip/hip_bf16.h>
#include <math.h>

typedef unsigned short u16;
typedef unsigned int u32;
typedef __attribute__((ext_vector_type(8))) short bf16x8;   // 8 bf16 = 4 VGPRs
typedef __attribute__((ext_vector_type(4))) float f32x4;

constexpr int Bc = 2, Sc = 2048, Dc = 2048, Hc = 16, HDc = 128;
constexpr int Mc = Bc * Sc;                     // 4096
constexpr float SCALE = 0.08838834764831845f;   // 1/sqrt(128)

__device__ inline u16 f2bf(float f) {
  __hip_bfloat16 h = __float2bfloat16(f);
  return __builtin_bit_cast(u16, h);
}

typedef const __attribute__((address_space(1))) u32 glb_u32;
typedef __attribute__((address_space(3))) u32 lds_u32;
__device__ inline void gload16(const void* g, void* l) {
  // async global->LDS, 16B/lane; LDS dest is wave-uniform base + lane*16
  __builtin_amdgcn_global_load_lds((glb_u32*)g, (lds_u32*)l, 16, 0, 0);
}

// ---------------- fp32 -> bf16 convert (hidden + 4 weights) ----------------
__global__ __launch_bounds__(256) void cvt5(
    const float* __restrict__ s0, u16* __restrict__ d0, int n0,
    const float* __restrict__ s1, u16* __restrict__ d1, int n1,
    const float* __restrict__ s2, u16* __restrict__ d2, int n2,
    const float* __restrict__ s3, u16* __restrict__ d3, int n3,
    const float* __restrict__ s4, u16* __restrict__ d4, int n4) {
  int i = blockIdx.x * 256 + threadIdx.x;   // float4 index
  const float* s; u16* d;
  if (i < n0) { s = s0; d = d0; }
  else { i -= n0;
    if (i < n1) { s = s1; d = d1; }
    else { i -= n1;
      if (i < n2) { s = s2; d = d2; }
      else { i -= n2;
        if (i < n3) { s = s3; d = d3; }
        else { i -= n3;
          if (i >= n4) return;
          s = s4; d = d4; } } } }
  float4 v = reinterpret_cast<const float4*>(s)[i];
  ushort4 o;
  o.x = f2bf(v.x); o.y = f2bf(v.y); o.z = f2bf(v.z); o.w = f2bf(v.w);
  reinterpret_cast<ushort4*>(d)[i] = o;
}

// ---------------- bf16 MFMA GEMM: C[M,N] = A[M,K] * W[N,K]^T + bias --------
// MODE 0: bf16 scatter to [B,H,S,HD], scaled; MODE 1: fp32 [M,N] to d_out;
// MODE 2: bf16 transposed scatter to [B,H,HD,S] with per-32 k-permutation
//         (PV B-operand order: slot s2*32+g*8+hi*4+lo2 <- k s2*32+hi*16+g*4+lo2)
constexpr int GBM = 128, GBN = 128, GBK = 64;

template <int MODE>
__global__ __launch_bounds__(256) void gemm_bf16(
    const u16* __restrict__ A, const u16* __restrict__ W,
    const float* __restrict__ bias, void* __restrict__ outp, float scale) {
  __shared__ u16 smem[17408];     // As[8192] | Bs[8192]; epilogue CT[128*136]
  u16* As = smem;
  u16* Bs = smem + 8192;
  char* Asb = (char*)As;
  char* Bsb = (char*)Bs;
  const int t = threadIdx.x;
  const int w = t >> 6, lane = t & 63, g = lane >> 4, c = lane & 15;
  const int wm = w >> 1, wn = w & 1;
  const int m0 = blockIdx.y * GBM, n0 = blockIdx.x * GBN;

  f32x4 acc[4][4];
#pragma unroll
  for (int m = 0; m < 4; ++m)
#pragma unroll
    for (int n = 0; n < 4; ++n) acc[m][n] = 0.f;

  for (int k0 = 0; k0 < Dc; k0 += GBK) {
#pragma unroll
    for (int i = 0; i < 4; ++i) {
      int u = i * 256 + t;
      int row = u >> 3, cu = u & 7;
      int ub = i * 256 + (t & 192);           // wave-uniform unit base
      gload16(A + (size_t)(m0 + row) * Dc + k0 + cu * 8, Asb + ub * 16);
      gload16(W + (size_t)(n0 + row) * Dc + k0 + cu * 8, Bsb + ub * 16);
    }
    __syncthreads();
#pragma unroll
    for (int s = 0; s < 2; ++s) {
      bf16x8 af[4], bfv[4];
#pragma unroll
      for (int m = 0; m < 4; ++m)
        af[m] = *(const bf16x8*)(Asb + (wm * 64 + m * 16 + c) * 128 + s * 64 + g * 16);
#pragma unroll
      for (int n = 0; n < 4; ++n)
        bfv[n] = *(const bf16x8*)(Bsb + (wn * 64 + n * 16 + c) * 128 + s * 64 + g * 16);
#pragma unroll
      for (int m = 0; m < 4; ++m)
#pragma unroll
        for (int n = 0; n < 4; ++n)
          acc[m][n] = __builtin_amdgcn_mfma_f32_16x16x32_bf16(af[m], bfv[n], acc[m][n], 0, 0, 0);
    }
    __syncthreads();
  }

  if (MODE == 2) {
    // transpose through LDS, then permuted u32-pair writes to [B,H,HD,S]
    u16* CT = smem;                           // [128 d][136 pitch] u16
    __syncthreads();
#pragma unroll
    for (int m = 0; m < 4; ++m)
#pragma unroll
      for (int n = 0; n < 4; ++n) {
        int lcol = wn * 64 + n * 16 + c;      // d (local)
        float bv = bias[n0 + lcol];
#pragma unroll
        for (int r = 0; r < 4; ++r) {
          int lrow = wm * 64 + m * 16 + g * 4 + r;   // s (local)
          CT[lcol * 136 + lrow] = f2bf(acc[m][n][r] + bv);
        }
      }
    __syncthreads();
    const int b = m0 >> 11, h = n0 >> 7, s0 = m0 & (Sc - 1);
    u16* op = (u16*)outp;
#pragma unroll
    for (int i = 0; i < 8; ++i) {
      int u = i * 256 + t;
      int d = u >> 4, su = u & 15;
      size_t gbase = ((size_t)((b * Hc + h) * HDc) + d) * Sc + s0;
#pragma unroll
      for (int p2 = 0; p2 < 4; ++p2) {
        int sl = su * 8 + p2 * 2;             // even local s
        u32 val = (u32)CT[d * 136 + sl] | ((u32)CT[d * 136 + sl + 1] << 16);
        int w6 = sl & 63, blk = sl >> 6;
        int slot = ((w6 >> 5) << 5) | (((w6 >> 2) & 3) << 3) |
                   (((w6 >> 4) & 1) << 2) | (w6 & 3);
        *(u32*)&op[gbase + blk * 64 + slot] = val;
      }
    }
    return;
  }

#pragma unroll
  for (int m = 0; m < 4; ++m)
#pragma unroll
    for (int n = 0; n < 4; ++n) {
      int col = n0 + wn * 64 + n * 16 + c;
      float bv = bias[col];
#pragma unroll
      for (int r = 0; r < 4; ++r) {
        int row = m0 + wm * 64 + m * 16 + g * 4 + r;
        float v = (acc[m][n][r] + bv) * scale;
        if (MODE == 0) {
          int b = row >> 11, si = row & (Sc - 1);
          int h = col >> 7, d = col & (HDc - 1);
          ((u16*)outp)[((size_t)((b * Hc + h) * Sc + si)) * HDc + d] = f2bf(v);
        } else {
          ((float*)outp)[(size_t)row * Dc + col] = v;
        }
      }
    }
}

// ---------------- bf16 MFMA flash attention (v5) ----------------
// 1024 blocks (XCD-swz), 256 thr = 4 waves, 16 q-rows/wave. Single-buffer
// K+V (32KB -> 4 blocks/CU; TLP hides staging per m114/R3 evidence).
// Swapped QK^T; P packed in-lane directly to the PV B-operand (V is
// k-permuted per 32-block by the MODE2 GEMM epilogue) -> zero shfl, zero
// P-LDS traffic.
__global__ __launch_bounds__(256, 4) void attn_mfma(
    const u16* __restrict__ Q, const u16* __restrict__ K,
    const u16* __restrict__ VT, const float* __restrict__ mask,
    u16* __restrict__ outb) {
  __shared__ u16 Ks[64 * 128];    // [k][d units, swizzled (cu&8)|((cu^k)&7)]
  __shared__ u16 Vt[128 * 64];    // [d][k units, swizzled (cu^d)&7], permuted k
  char* Ksb = (char*)Ks;
  char* Vtb = (char*)Vt;
  const int t = threadIdx.x, w = t >> 6, lane = t & 63, g = lane >> 4, c = lane & 15;
  const int bid = blockIdx.x;
  const int nid = (bid & 7) * 128 + (bid >> 3);  // 1024%8==0 bijective
  const int bh = nid >> 5;                       // head (4 heads/XCD)
  const int q0 = (nid & 31) * 64;
  const int bq = bh >> 4, h = bh & 15;
  const u16* Qp = Q + ((size_t)bh << 18);
  const u16* Kp = K + ((size_t)bh << 18);
  const u16* VTp = VT + ((size_t)bh << 18);

  // Q fragments (pre-scaled by 1/sqrt(HD)); B-operand of swapped QK^T
  bf16x8 qf[4];
  {
    int qr = q0 + w * 16 + c;
#pragma unroll
    for (int d0 = 0; d0 < 4; ++d0)
      qf[d0] = *(const bf16x8*)(Qp + (size_t)qr * HDc + d0 * 32 + g * 8);
  }

  f32x4 po[8];                     // O^T acc: d = m*16+g*4+r, q = c
#pragma unroll
  for (int m = 0; m < 8; ++m) po[m] = 0.f;
  float lsum = 0.f;
  const float* mrow = mask + ((size_t)bq * Sc + q0 + w * 16 + c) * Sc;

#pragma unroll 1
  for (int kt = 0; kt < 32; ++kt) {
    const int k0 = kt * 64;
    // stage K: 1024 16B-units, source pre-swizzled, LDS linear
#pragma unroll
    for (int i = 0; i < 4; ++i) {
      int u = i * 256 + t, row = u >> 4, p = u & 15;
      int cu = (p & 8) | ((p ^ row) & 7);
      gload16(Kp + (size_t)(k0 + row) * HDc + cu * 8,
              Ksb + (i * 256 + (t & 192)) * 16);
    }
    // stage V^T (k-permuted in global): 1024 16B-units
#pragma unroll
    for (int i = 0; i < 4; ++i) {
      int u = i * 256 + t, d = u >> 3, p = u & 7;
      int cu = (p ^ d) & 7;
      gload16(VTp + (size_t)d * Sc + k0 + cu * 8,
              Vtb + (i * 256 + (t & 192)) * 16);
    }
    // mask tile: k-contiguous float4 for q = c
    float4 mk[4];
#pragma unroll
    for (int n = 0; n < 4; ++n)
      mk[n] = *(const float4*)(mrow + k0 + n * 16 + g * 4);
    __syncthreads();               // drains staging (+mask loads)

    // QK^T (swapped): S^T[k][q], k = n*16+g*4+r, q = c
    f32x4 sfr[4];
#pragma unroll
    for (int n = 0; n < 4; ++n) sfr[n] = 0.f;
    __builtin_amdgcn_s_setprio(1);
#pragma unroll
    for (int ds = 0; ds < 4; ++ds)
#pragma unroll
      for (int n = 0; n < 4; ++n) {
        int row = n * 16 + c;
        int cu = ds * 4 + g;
        int scu = (cu & 8) | ((cu ^ row) & 7);
        bf16x8 kf = *(const bf16x8*)(Ksb + row * 256 + scu * 16);
        sfr[n] = __builtin_amdgcn_mfma_f32_16x16x32_bf16(kf, qf[ds], sfr[n], 0, 0, 0);
      }
    __builtin_amdgcn_s_setprio(0);

    // no-max softmax, in-lane pack straight into PV B-operand layout
    u32 w01[4], w23[4];
#pragma unroll
    for (int n = 0; n < 4; ++n) {
      float p0 = __expf(sfr[n][0] + mk[n].x);
      float p1 = __expf(sfr[n][1] + mk[n].y);
      float p2 = __expf(sfr[n][2] + mk[n].z);
      float p3 = __expf(sfr[n][3] + mk[n].w);
      lsum += (p0 + p1) + (p2 + p3);
      w01[n] = (u32)f2bf(p0) | ((u32)f2bf(p1) << 16);
      w23[n] = (u32)f2bf(p2) | ((u32)f2bf(p3) << 16);
    }

    // PV: O^T += V^T * P^T  (pf needs zero cross-lane thanks to V k-perm)
    __builtin_amdgcn_s_setprio(1);
#pragma unroll
    for (int s2 = 0; s2 < 2; ++s2) {
      uint4 pw;
      pw.x = w01[s2 * 2];
      pw.y = w23[s2 * 2];
      pw.z = w01[s2 * 2 + 1];
      pw.w = w23[s2 * 2 + 1];
      bf16x8 pf = __builtin_bit_cast(bf16x8, pw);
#pragma unroll
      for (int m = 0; m < 8; ++m) {
        int d = m * 16 + c;
        int scuv = ((s2 * 4 + g) ^ (d & 7)) & 7;
        bf16x8 vf = *(const bf16x8*)(Vtb + d * 128 + scuv * 16);
        po[m] = __builtin_amdgcn_mfma_f32_16x16x32_bf16(vf, pf, po[m], 0, 0, 0);
      }
    }
    __builtin_amdgcn_s_setprio(0);
    __syncthreads();               // compute done before next stage overwrite
  }

  // final l reduction (lanes c, c+16, c+32, c+48 hold partials of same q)
  lsum += __shfl_xor(lsum, 16, 64);
  lsum += __shfl_xor(lsum, 32, 64);
  const float rlq = 1.0f / lsum;
  const int qg = q0 + w * 16 + c;
  u16* obase = outb + ((size_t)(bq * Sc + qg)) * Dc + h * HDc;
#pragma unroll
  for (int m = 0; m < 8; ++m) {
    ushort4 o4;
    o4.x = f2bf(po[m][0] * rlq);
    o4.y = f2bf(po[m][1] * rlq);
    o4.z = f2bf(po[m][2] * rlq);
    o4.w = f2bf(po[m][3] * rlq);
    *(ushort4*)(obase + m * 16 + g * 4) = o4;
  }
}

// ---------------- launch ----------------
extern "C" void kernel_launch(void* const* d_in, const int* in_sizes, int n_in,
                              void* d_out, int out_size, void* d_ws,
                              size_t ws_size, hipStream_t stream) {
  const float* hs   = (const float*)d_in[0];
  const float* mask = (const float*)d_in[1];
  const float* Wq   = (const float*)d_in[2];
  const float* bqp  = (const float*)d_in[3];
  const float* Wk   = (const float*)d_in[4];
  const float* bkp  = (const float*)d_in[5];
  const float* Wv   = (const float*)d_in[6];
  const float* bvp  = (const float*)d_in[7];
  const float* Wo   = (const float*)d_in[8];
  const float* bop  = (const float*)d_in[9];

  u16* Xb  = (u16*)d_ws;                 // [4096][2048] bf16
  u16* Wqb = Xb + (size_t)Mc * Dc;
  u16* Wkb = Wqb + (size_t)Dc * Dc;
  u16* Wvb = Wkb + (size_t)Dc * Dc;
  u16* Wob = Wvb + (size_t)Dc * Dc;
  u16* qb  = Wob + (size_t)Dc * Dc;      // [B,H,S,HD] bf16 (pre-scaled)
  u16* kb  = qb + (size_t)Mc * Dc;       // [B,H,S,HD] bf16
  u16* vtb = kb + (size_t)Mc * Dc;       // [B,H,HD,S] bf16, k-permuted /32
  u16* ab  = vtb + (size_t)Mc * Dc;      // [B,S,D] bf16

  const int nh4 = Mc * Dc / 4;
  const int nw4 = Dc * Dc / 4;
  cvt5<<<dim3((nh4 + 4 * nw4) / 256), dim3(256), 0, stream>>>(
      hs, Xb, nh4, Wq, Wqb, nw4, Wk, Wkb, nw4, Wv, Wvb, nw4, Wo, Wob, nw4);

  dim3 blk(256);
  dim3 gg(Dc / GBN, Mc / GBM);           // (16, 32)
  gemm_bf16<0><<<gg, blk, 0, stream>>>(Xb, Wqb, bqp, qb, SCALE);
  gemm_bf16<0><<<gg, blk, 0, stream>>>(Xb, Wkb, bkp, kb, 1.0f);
  gemm_bf16<2><<<gg, blk, 0, stream>>>(Xb, Wvb, bvp, vtb, 1.0f);
  attn_mfma<<<dim3(1024), blk, 0, stream>>>(qb, kb, vtb, mask, ab);
  gemm_bf16<1><<<gg, blk, 0, stream>>>(ab, Wob, bop, d_out, 1.0f);
}

// Round 7
// 324.018 us; speedup vs baseline: 1.2117x; 1.0643x over previous
//
#include <hip/hip_runtime.h>
#include <hip/hip_bf16.h>
#include <math.h>

typedef unsigned short u16;
typedef unsigned int u32;
typedef __attribute__((ext_vector_type(8))) short bf16x8;   // 8 bf16 = 4 VGPRs
typedef __attribute__((ext_vector_type(4))) float f32x4;

constexpr int Bc = 2, Sc = 2048, Dc = 2048, Hc = 16, HDc = 128;
constexpr int Mc = Bc * Sc;                     // 4096
constexpr float SCALE = 0.08838834764831845f;   // 1/sqrt(128)

__device__ inline u16 f2bf(float f) {
  __hip_bfloat16 h = __float2bfloat16(f);
  return __builtin_bit_cast(u16, h);
}

typedef const __attribute__((address_space(1))) u32 glb_u32;
typedef __attribute__((address_space(3))) u32 lds_u32;
__device__ inline void gload16(const void* g, void* l) {
  // async global->LDS, 16B/lane; LDS dest is wave-uniform base + lane*16
  __builtin_amdgcn_global_load_lds((glb_u32*)g, (lds_u32*)l, 16, 0, 0);
}

// ---------------- fp32 -> bf16 convert (hidden + 4 weights) ----------------
__global__ __launch_bounds__(256) void cvt5(
    const float* __restrict__ s0, u16* __restrict__ d0, int n0,
    const float* __restrict__ s1, u16* __restrict__ d1, int n1,
    const float* __restrict__ s2, u16* __restrict__ d2, int n2,
    const float* __restrict__ s3, u16* __restrict__ d3, int n3,
    const float* __restrict__ s4, u16* __restrict__ d4, int n4) {
  int i = blockIdx.x * 256 + threadIdx.x;   // float4 index
  const float* s; u16* d;
  if (i < n0) { s = s0; d = d0; }
  else { i -= n0;
    if (i < n1) { s = s1; d = d1; }
    else { i -= n1;
      if (i < n2) { s = s2; d = d2; }
      else { i -= n2;
        if (i < n3) { s = s3; d = d3; }
        else { i -= n3;
          if (i >= n4) return;
          s = s4; d = d4; } } } }
  float4 v = reinterpret_cast<const float4*>(s)[i];
  ushort4 o;
  o.x = f2bf(v.x); o.y = f2bf(v.y); o.z = f2bf(v.z); o.w = f2bf(v.w);
  reinterpret_cast<ushort4*>(d)[i] = o;
}

// ---------------- bf16 MFMA GEMM: C[M,N] = A[M,K] * W[N,K]^T + bias --------
// MODE 0: bf16 scatter to [B,H,S,HD], scaled; MODE 1: fp32 [M,N] to d_out;
// MODE 2: bf16 transposed scatter to [B,H,HD,S] with per-32 k-permutation
//         (PV B-operand order: slot s2*32+g*8+hi*4+lo2 <- k s2*32+hi*16+g*4+lo2)
constexpr int GBM = 128, GBN = 128, GBK = 64;

template <int MODE>
__global__ __launch_bounds__(256) void gemm_bf16(
    const u16* __restrict__ A, const u16* __restrict__ W,
    const float* __restrict__ bias, void* __restrict__ outp, float scale) {
  __shared__ u16 smem[17408];     // As[8192] | Bs[8192]; epilogue CT[128*136]
  u16* As = smem;
  u16* Bs = smem + 8192;
  char* Asb = (char*)As;
  char* Bsb = (char*)Bs;
  const int t = threadIdx.x;
  const int w = t >> 6, lane = t & 63, g = lane >> 4, c = lane & 15;
  const int wm = w >> 1, wn = w & 1;
  const int m0 = blockIdx.y * GBM, n0 = blockIdx.x * GBN;

  f32x4 acc[4][4];
#pragma unroll
  for (int m = 0; m < 4; ++m)
#pragma unroll
    for (int n = 0; n < 4; ++n) acc[m][n] = 0.f;

  for (int k0 = 0; k0 < Dc; k0 += GBK) {
#pragma unroll
    for (int i = 0; i < 4; ++i) {
      int u = i * 256 + t;
      int row = u >> 3, cu = u & 7;
      int ub = i * 256 + (t & 192);           // wave-uniform unit base
      gload16(A + (size_t)(m0 + row) * Dc + k0 + cu * 8, Asb + ub * 16);
      gload16(W + (size_t)(n0 + row) * Dc + k0 + cu * 8, Bsb + ub * 16);
    }
    __syncthreads();
#pragma unroll
    for (int s = 0; s < 2; ++s) {
      bf16x8 af[4], bfv[4];
#pragma unroll
      for (int m = 0; m < 4; ++m)
        af[m] = *(const bf16x8*)(Asb + (wm * 64 + m * 16 + c) * 128 + s * 64 + g * 16);
#pragma unroll
      for (int n = 0; n < 4; ++n)
        bfv[n] = *(const bf16x8*)(Bsb + (wn * 64 + n * 16 + c) * 128 + s * 64 + g * 16);
#pragma unroll
      for (int m = 0; m < 4; ++m)
#pragma unroll
        for (int n = 0; n < 4; ++n)
          acc[m][n] = __builtin_amdgcn_mfma_f32_16x16x32_bf16(af[m], bfv[n], acc[m][n], 0, 0, 0);
    }
    __syncthreads();
  }

  if (MODE == 2) {
    // transpose through LDS, then permuted u32-pair writes to [B,H,HD,S]
    u16* CT = smem;                           // [128 d][136 pitch] u16
    __syncthreads();
#pragma unroll
    for (int m = 0; m < 4; ++m)
#pragma unroll
      for (int n = 0; n < 4; ++n) {
        int lcol = wn * 64 + n * 16 + c;      // d (local)
        float bv = bias[n0 + lcol];
#pragma unroll
        for (int r = 0; r < 4; ++r) {
          int lrow = wm * 64 + m * 16 + g * 4 + r;   // s (local)
          CT[lcol * 136 + lrow] = f2bf(acc[m][n][r] + bv);
        }
      }
    __syncthreads();
    const int b = m0 >> 11, h = n0 >> 7, s0 = m0 & (Sc - 1);
    u16* op = (u16*)outp;
#pragma unroll
    for (int i = 0; i < 8; ++i) {
      int u = i * 256 + t;
      int d = u >> 4, su = u & 15;
      size_t gbase = ((size_t)((b * Hc + h) * HDc) + d) * Sc + s0;
#pragma unroll
      for (int p2 = 0; p2 < 4; ++p2) {
        int sl = su * 8 + p2 * 2;             // even local s
        u32 val = (u32)CT[d * 136 + sl] | ((u32)CT[d * 136 + sl + 1] << 16);
        int w6 = sl & 63, blk = sl >> 6;
        int slot = ((w6 >> 5) << 5) | (((w6 >> 2) & 3) << 3) |
                   (((w6 >> 4) & 1) << 2) | (w6 & 3);
        *(u32*)&op[gbase + blk * 64 + slot] = val;
      }
    }
    return;
  }

#pragma unroll
  for (int m = 0; m < 4; ++m)
#pragma unroll
    for (int n = 0; n < 4; ++n) {
      int col = n0 + wn * 64 + n * 16 + c;
      float bv = bias[col];
#pragma unroll
      for (int r = 0; r < 4; ++r) {
        int row = m0 + wm * 64 + m * 16 + g * 4 + r;
        float v = (acc[m][n][r] + bv) * scale;
        if (MODE == 0) {
          int b = row >> 11, si = row & (Sc - 1);
          int h = col >> 7, d = col & (HDc - 1);
          ((u16*)outp)[((size_t)((b * Hc + h) * Sc + si)) * HDc + d] = f2bf(v);
        } else {
          ((float*)outp)[(size_t)row * Dc + col] = v;
        }
      }
    }
}

// ---------------- bf16 MFMA flash attention (v6) ----------------
// 1024 blocks (XCD-swz), 128 thr = 2 waves, 32 q-rows/wave (two 16-q sets
// sharing every K/V fragment read -> LDS bytes per MFMA halved vs v5).
// Single-buffer K+V (32KB -> 4 blocks/CU). Swapped QK^T; in-lane P pack
// (V k-permuted per 32-block by MODE2 epilogue) -> zero shfl, zero P-LDS.
__global__ __launch_bounds__(128, 2) void attn_mfma(
    const u16* __restrict__ Q, const u16* __restrict__ K,
    const u16* __restrict__ VT, const float* __restrict__ mask,
    u16* __restrict__ outb) {
  __shared__ u16 Ks[64 * 128];    // [k][d units, swizzled (cu&8)|((cu^k)&7)]
  __shared__ u16 Vt[128 * 64];    // [d][k units, swizzled (cu^d)&7], permuted k
  char* Ksb = (char*)Ks;
  char* Vtb = (char*)Vt;
  const int t = threadIdx.x, w = t >> 6, lane = t & 63, g = lane >> 4, c = lane & 15;
  const int bid = blockIdx.x;
  const int nid = (bid & 7) * 128 + (bid >> 3);  // 1024%8==0 bijective
  const int bh = nid >> 5;                       // head (4 heads/XCD)
  const int q0 = (nid & 31) * 64;                // 64 q-rows per block
  const int bq = bh >> 4, h = bh & 15;
  const u16* Qp = Q + ((size_t)bh << 18);
  const u16* Kp = K + ((size_t)bh << 18);
  const u16* VTp = VT + ((size_t)bh << 18);

  // Q fragments for both q-sets (pre-scaled); B-operand of swapped QK^T
  bf16x8 qf0[4], qf1[4];
  {
    int qr0 = q0 + w * 32 + c;
    int qr1 = qr0 + 16;
#pragma unroll
    for (int d0 = 0; d0 < 4; ++d0) {
      qf0[d0] = *(const bf16x8*)(Qp + (size_t)qr0 * HDc + d0 * 32 + g * 8);
      qf1[d0] = *(const bf16x8*)(Qp + (size_t)qr1 * HDc + d0 * 32 + g * 8);
    }
  }

  f32x4 po0[8], po1[8];            // O^T acc: d = m*16+g*4+r, q = c (per set)
#pragma unroll
  for (int m = 0; m < 8; ++m) { po0[m] = 0.f; po1[m] = 0.f; }
  float lsum0 = 0.f, lsum1 = 0.f;
  const float* mrow0 = mask + ((size_t)bq * Sc + q0 + w * 32 + c) * Sc;
  const float* mrow1 = mrow0 + (size_t)16 * Sc;

#pragma unroll 1
  for (int kt = 0; kt < 32; ++kt) {
    const int k0 = kt * 64;
    // stage K: 1024 16B-units over 128 lanes, source pre-swizzled, LDS linear
#pragma unroll
    for (int i = 0; i < 8; ++i) {
      int u = i * 128 + t, row = u >> 4, p = u & 15;
      int cu = (p & 8) | ((p ^ row) & 7);
      gload16(Kp + (size_t)(k0 + row) * HDc + cu * 8,
              Ksb + (i * 128 + (t & 64)) * 16);
    }
    // stage V^T (k-permuted in global): 1024 16B-units
#pragma unroll
    for (int i = 0; i < 8; ++i) {
      int u = i * 128 + t, d = u >> 3, p = u & 7;
      int cu = (p ^ d) & 7;
      gload16(VTp + (size_t)d * Sc + k0 + cu * 8,
              Vtb + (i * 128 + (t & 64)) * 16);
    }
    // mask tiles: k-contiguous float4 for q = c (both sets)
    float4 mk0[4], mk1[4];
#pragma unroll
    for (int n = 0; n < 4; ++n) {
      mk0[n] = *(const float4*)(mrow0 + k0 + n * 16 + g * 4);
      mk1[n] = *(const float4*)(mrow1 + k0 + n * 16 + g * 4);
    }
    __syncthreads();               // drains staging

    // QK^T (swapped): S^T[k][q]; each kf shared by both q-sets
    f32x4 sfr0[4], sfr1[4];
#pragma unroll
    for (int n = 0; n < 4; ++n) { sfr0[n] = 0.f; sfr1[n] = 0.f; }
    __builtin_amdgcn_s_setprio(1);
#pragma unroll
    for (int ds = 0; ds < 4; ++ds)
#pragma unroll
      for (int n = 0; n < 4; ++n) {
        int row = n * 16 + c;
        int cu = ds * 4 + g;
        int scu = (cu & 8) | ((cu ^ row) & 7);
        bf16x8 kf = *(const bf16x8*)(Ksb + row * 256 + scu * 16);
        sfr0[n] = __builtin_amdgcn_mfma_f32_16x16x32_bf16(kf, qf0[ds], sfr0[n], 0, 0, 0);
        sfr1[n] = __builtin_amdgcn_mfma_f32_16x16x32_bf16(kf, qf1[ds], sfr1[n], 0, 0, 0);
      }
    __builtin_amdgcn_s_setprio(0);

    // no-max softmax, in-lane pack straight into PV B-operand layout
    u32 a01[4], a23[4], b01[4], b23[4];
#pragma unroll
    for (int n = 0; n < 4; ++n) {
      float p0 = __expf(sfr0[n][0] + mk0[n].x);
      float p1 = __expf(sfr0[n][1] + mk0[n].y);
      float p2 = __expf(sfr0[n][2] + mk0[n].z);
      float p3 = __expf(sfr0[n][3] + mk0[n].w);
      lsum0 += (p0 + p1) + (p2 + p3);
      a01[n] = (u32)f2bf(p0) | ((u32)f2bf(p1) << 16);
      a23[n] = (u32)f2bf(p2) | ((u32)f2bf(p3) << 16);
      float r0 = __expf(sfr1[n][0] + mk1[n].x);
      float r1 = __expf(sfr1[n][1] + mk1[n].y);
      float r2 = __expf(sfr1[n][2] + mk1[n].z);
      float r3 = __expf(sfr1[n][3] + mk1[n].w);
      lsum1 += (r0 + r1) + (r2 + r3);
      b01[n] = (u32)f2bf(r0) | ((u32)f2bf(r1) << 16);
      b23[n] = (u32)f2bf(r2) | ((u32)f2bf(r3) << 16);
    }

    // PV: O^T += V^T * P^T; each vf shared by both q-sets
    __builtin_amdgcn_s_setprio(1);
#pragma unroll
    for (int s2 = 0; s2 < 2; ++s2) {
      uint4 pw0, pw1;
      pw0.x = a01[s2 * 2]; pw0.y = a23[s2 * 2];
      pw0.z = a01[s2 * 2 + 1]; pw0.w = a23[s2 * 2 + 1];
      pw1.x = b01[s2 * 2]; pw1.y = b23[s2 * 2];
      pw1.z = b01[s2 * 2 + 1]; pw1.w = b23[s2 * 2 + 1];
      bf16x8 pf0 = __builtin_bit_cast(bf16x8, pw0);
      bf16x8 pf1 = __builtin_bit_cast(bf16x8, pw1);
#pragma unroll
      for (int m = 0; m < 8; ++m) {
        int d = m * 16 + c;
        int scuv = ((s2 * 4 + g) ^ (d & 7)) & 7;
        bf16x8 vf = *(const bf16x8*)(Vtb + d * 128 + scuv * 16);
        po0[m] = __builtin_amdgcn_mfma_f32_16x16x32_bf16(vf, pf0, po0[m], 0, 0, 0);
        po1[m] = __builtin_amdgcn_mfma_f32_16x16x32_bf16(vf, pf1, po1[m], 0, 0, 0);
      }
    }
    __builtin_amdgcn_s_setprio(0);
    __syncthreads();               // compute done before next stage overwrite
  }

  // final l reduction (lanes c, c+16, c+32, c+48 hold partials of same q)
  lsum0 += __shfl_xor(lsum0, 16, 64);
  lsum0 += __shfl_xor(lsum0, 32, 64);
  lsum1 += __shfl_xor(lsum1, 16, 64);
  lsum1 += __shfl_xor(lsum1, 32, 64);
  const float rl0 = 1.0f / lsum0;
  const float rl1 = 1.0f / lsum1;
  const int qg0 = q0 + w * 32 + c;
  u16* ob0 = outb + ((size_t)(bq * Sc + qg0)) * Dc + h * HDc;
  u16* ob1 = ob0 + (size_t)16 * Dc;
#pragma unroll
  for (int m = 0; m < 8; ++m) {
    ushort4 o4;
    o4.x = f2bf(po0[m][0] * rl0);
    o4.y = f2bf(po0[m][1] * rl0);
    o4.z = f2bf(po0[m][2] * rl0);
    o4.w = f2bf(po0[m][3] * rl0);
    *(ushort4*)(ob0 + m * 16 + g * 4) = o4;
    ushort4 o5;
    o5.x = f2bf(po1[m][0] * rl1);
    o5.y = f2bf(po1[m][1] * rl1);
    o5.z = f2bf(po1[m][2] * rl1);
    o5.w = f2bf(po1[m][3] * rl1);
    *(ushort4*)(ob1 + m * 16 + g * 4) = o5;
  }
}

// ---------------- launch ----------------
extern "C" void kernel_launch(void* const* d_in, const int* in_sizes, int n_in,
                              void* d_out, int out_size, void* d_ws,
                              size_t ws_size, hipStream_t stream) {
  const float* hs   = (const float*)d_in[0];
  const float* mask = (const float*)d_in[1];
  const float* Wq   = (const float*)d_in[2];
  const float* bqp  = (const float*)d_in[3];
  const float* Wk   = (const float*)d_in[4];
  const float* bkp  = (const float*)d_in[5];
  const float* Wv   = (const float*)d_in[6];
  const float* bvp  = (const float*)d_in[7];
  const float* Wo   = (const float*)d_in[8];
  const float* bop  = (const float*)d_in[9];

  u16* Xb  = (u16*)d_ws;                 // [4096][2048] bf16
  u16* Wqb = Xb + (size_t)Mc * Dc;
  u16* Wkb = Wqb + (size_t)Dc * Dc;
  u16* Wvb = Wkb + (size_t)Dc * Dc;
  u16* Wob = Wvb + (size_t)Dc * Dc;
  u16* qb  = Wob + (size_t)Dc * Dc;      // [B,H,S,HD] bf16 (pre-scaled)
  u16* kb  = qb + (size_t)Mc * Dc;       // [B,H,S,HD] bf16
  u16* vtb = kb + (size_t)Mc * Dc;       // [B,H,HD,S] bf16, k-permuted /32
  u16* ab  = vtb + (size_t)Mc * Dc;      // [B,S,D] bf16

  const int nh4 = Mc * Dc / 4;
  const int nw4 = Dc * Dc / 4;
  cvt5<<<dim3((nh4 + 4 * nw4) / 256), dim3(256), 0, stream>>>(
      hs, Xb, nh4, Wq, Wqb, nw4, Wk, Wkb, nw4, Wv, Wvb, nw4, Wo, Wob, nw4);

  dim3 blk(256);
  dim3 gg(Dc / GBN, Mc / GBM);           // (16, 32)
  gemm_bf16<0><<<gg, blk, 0, stream>>>(Xb, Wqb, bqp, qb, SCALE);
  gemm_bf16<0><<<gg, blk, 0, stream>>>(Xb, Wkb, bkp, kb, 1.0f);
  gemm_bf16<2><<<gg, blk, 0, stream>>>(Xb, Wvb, bvp, vtb, 1.0f);
  attn_mfma<<<dim3(1024), dim3(128), 0, stream>>>(qb, kb, vtb, mask, ab);
  gemm_bf16<1><<<gg, blk, 0, stream>>>(ab, Wob, bop, d_out, 1.0f);
}